// Round 1
// baseline (1783.611 us; speedup 1.0000x reference)
//
#include <hip/hip_runtime.h>
#include <math.h>

// Problem constants (from reference): B=1024, T=1024, D_IN=256, D=256, M=10, R=2
constexpr int Bc   = 1024;
constexpr int Tc   = 1024;
constexpr int DINc = 256;
constexpr int Dc   = 256;
constexpr int Mc   = 10;

__device__ __forceinline__ float sigmoidf(float v) {
    return 1.0f / (1.0f + expf(-v));
}

// One block per batch row b; 256 threads, thread j owns output column j.
__global__ __launch_bounds__(256) void rnn_cell_kernel(
    const float* __restrict__ x,
    const float* __restrict__ h_history,
    const float* __restrict__ W_in_w, const float* __restrict__ W_in_b,
    const float* __restrict__ W_k_w,  const float* __restrict__ W_k_b,
    const float* __restrict__ W_v_w,  const float* __restrict__ W_v_b,
    const float* __restrict__ W_bl_w, const float* __restrict__ W_bl_b,
    const int* __restrict__ jumps, const int* __restrict__ cur_p,
    float* __restrict__ out_h, float* __restrict__ out_y,
    float* __restrict__ out_hist)
{
    const int b   = blockIdx.x;
    const int tid = threadIdx.x;
    const int cur = *cur_p;

    __shared__ __align__(16) float x_sh[DINc];
    __shared__ __align__(16) float H_sh[Mc][Dc];
    __shared__ __align__(16) float h_sh[Dc];
    __shared__ float red_sh[Mc][4];   // per-wave score partials (4 waves)

    // ---- stage x[b] and the M gathered history rows into LDS ----
    x_sh[tid] = x[(size_t)b * DINc + tid];
    #pragma unroll
    for (int m = 0; m < Mc; ++m) {
        int idx = cur - jumps[m];
        if (idx < 0) idx = 0;
        H_sh[m][tid] = h_history[(size_t)b * Tc * Dc + (size_t)idx * Dc + tid];
    }
    __syncthreads();

    // ---- q[j] = x . W_in[:,j] + b_in[j] ----
    float q = W_in_b[tid];
    for (int i = 0; i < DINc; i += 4) {
        float4 xv = *(const float4*)&x_sh[i];
        q = fmaf(xv.x, W_in_w[(i + 0) * Dc + tid], q);
        q = fmaf(xv.y, W_in_w[(i + 1) * Dc + tid], q);
        q = fmaf(xv.z, W_in_w[(i + 2) * Dc + tid], q);
        q = fmaf(xv.w, W_in_w[(i + 3) * Dc + tid], q);
    }

    // ---- K[m][j], V[m][j] for all m in one pass over W_k/W_v ----
    float k_acc[Mc], v_acc[Mc];
    {
        const float kb = W_k_b[tid];
        const float vb = W_v_b[tid];
        #pragma unroll
        for (int m = 0; m < Mc; ++m) { k_acc[m] = kb; v_acc[m] = vb; }
    }
    for (int i = 0; i < Dc; i += 4) {
        float wk0 = W_k_w[(i + 0) * Dc + tid];
        float wk1 = W_k_w[(i + 1) * Dc + tid];
        float wk2 = W_k_w[(i + 2) * Dc + tid];
        float wk3 = W_k_w[(i + 3) * Dc + tid];
        float wv0 = W_v_w[(i + 0) * Dc + tid];
        float wv1 = W_v_w[(i + 1) * Dc + tid];
        float wv2 = W_v_w[(i + 2) * Dc + tid];
        float wv3 = W_v_w[(i + 3) * Dc + tid];
        #pragma unroll
        for (int m = 0; m < Mc; ++m) {
            float4 hv = *(const float4*)&H_sh[m][i];   // LDS broadcast read
            k_acc[m] = fmaf(hv.x, wk0, k_acc[m]);
            k_acc[m] = fmaf(hv.y, wk1, k_acc[m]);
            k_acc[m] = fmaf(hv.z, wk2, k_acc[m]);
            k_acc[m] = fmaf(hv.w, wk3, k_acc[m]);
            v_acc[m] = fmaf(hv.x, wv0, v_acc[m]);
            v_acc[m] = fmaf(hv.y, wv1, v_acc[m]);
            v_acc[m] = fmaf(hv.z, wv2, v_acc[m]);
            v_acc[m] = fmaf(hv.w, wv3, v_acc[m]);
        }
    }

    // ---- scores[m] = (q . K[m]) / 16 : block reduction ----
    const int lane = tid & 63;
    const int wave = tid >> 6;
    #pragma unroll
    for (int m = 0; m < Mc; ++m) {
        float p = q * k_acc[m];
        #pragma unroll
        for (int off = 32; off > 0; off >>= 1)
            p += __shfl_down(p, off, 64);
        if (lane == 0) red_sh[m][wave] = p;
    }
    __syncthreads();

    // ---- softmax over M (redundant per thread, M=10 tiny) ----
    float attn[Mc];
    {
        float sc[Mc];
        #pragma unroll
        for (int m = 0; m < Mc; ++m)
            sc[m] = (red_sh[m][0] + red_sh[m][1] + red_sh[m][2] + red_sh[m][3])
                    * (1.0f / 16.0f);   // scale = sqrt(D) = 16
        float mx = sc[0];
        #pragma unroll
        for (int m = 1; m < Mc; ++m) mx = fmaxf(mx, sc[m]);
        float s = 0.0f;
        #pragma unroll
        for (int m = 0; m < Mc; ++m) { attn[m] = expf(sc[m] - mx); s += attn[m]; }
        float inv = 1.0f / s;
        #pragma unroll
        for (int m = 0; m < Mc; ++m) attn[m] *= inv;
    }

    // ---- rs, h ----
    float rs = 0.0f;
    #pragma unroll
    for (int m = 0; m < Mc; ++m) rs = fmaf(attn[m], v_acc[m], rs);
    float h = sigmoidf(q + rs);

    h_sh[tid] = h;
    out_h[(size_t)b * Dc + tid] = h;
    // overwrite the current_index slice of new_history (memcpy ran before us)
    out_hist[(size_t)b * Tc * Dc + (size_t)cur * Dc + tid] = h;
    __syncthreads();

    // ---- y[j] = sigmoid(h . W_bl[:,j] + b_bl[j] + h[j]) ----
    float yv = W_bl_b[tid] + h;
    for (int i = 0; i < Dc; i += 4) {
        float4 hv = *(const float4*)&h_sh[i];
        yv = fmaf(hv.x, W_bl_w[(i + 0) * Dc + tid], yv);
        yv = fmaf(hv.y, W_bl_w[(i + 1) * Dc + tid], yv);
        yv = fmaf(hv.z, W_bl_w[(i + 2) * Dc + tid], yv);
        yv = fmaf(hv.w, W_bl_w[(i + 3) * Dc + tid], yv);
    }
    out_y[(size_t)b * Dc + tid] = sigmoidf(yv);
}

extern "C" void kernel_launch(void* const* d_in, const int* in_sizes, int n_in,
                              void* d_out, int out_size, void* d_ws, size_t ws_size,
                              hipStream_t stream) {
    const float* x      = (const float*)d_in[0];
    const float* hist   = (const float*)d_in[1];
    const float* W_in_w = (const float*)d_in[2];
    const float* W_in_b = (const float*)d_in[3];
    const float* W_k_w  = (const float*)d_in[4];
    const float* W_k_b  = (const float*)d_in[5];
    const float* W_v_w  = (const float*)d_in[6];
    const float* W_v_b  = (const float*)d_in[7];
    const float* W_bl_w = (const float*)d_in[8];
    const float* W_bl_b = (const float*)d_in[9];
    const int*   jumps  = (const int*)d_in[10];
    const int*   cur    = (const int*)d_in[11];

    float* out      = (float*)d_out;
    float* out_h    = out;                          // (B, D)
    float* out_y    = out + (size_t)Bc * Dc;        // (B, D)
    float* out_hist = out + (size_t)2 * Bc * Dc;    // (B, T, D)

    // Bulk copy h_history -> new_history (1.07 GB), then the kernel overwrites
    // the current_index slice. Same stream => ordered; capture-safe.
    hipMemcpyAsync(out_hist, hist, (size_t)Bc * Tc * Dc * sizeof(float),
                   hipMemcpyDeviceToDevice, stream);

    rnn_cell_kernel<<<Bc, Dc, 0, stream>>>(
        x, hist, W_in_w, W_in_b, W_k_w, W_k_b, W_v_w, W_v_b,
        W_bl_w, W_bl_b, jumps, cur, out_h, out_y, out_hist);
}